// Round 1
// 189.318 us; speedup vs baseline: 1.0534x; 1.0534x over previous
//
#include <hip/hip_runtime.h>
#include <float.h>

#define N_VOX 32768
#define N_CODES 8192
#define DIM 64

// output float offsets (flat, in return order)
#define Q_OFF 0
#define VQ_OFF (N_VOX * DIM)      // 2097152
#define CM_OFF (VQ_OFF + 1)
#define IDX_OFF (VQ_OFF + 2)

// workspace float offsets
#define WS_ACC 0
#define WS_CNT 1                      // int: blocks-done counter
#define WS_ESQH 64                    // 8192 floats: ||e||^2 / 2
#define WS_IDX (WS_ESQH + N_CODES)    // (unused now, layout kept)
#define WS_EHI (WS_IDX + N_VOX)       // codebook hi-plane f16 (1 MB)
#define WS_ELO (WS_EHI + N_CODES * DIM / 2)  // lo-plane f16 (1 MB)

typedef _Float16 half8 __attribute__((ext_vector_type(8)));
typedef float floatx4 __attribute__((ext_vector_type(4)));

// async global->LDS, 16 B per lane; lds dest must be wave-uniform base (+lane*16)
__device__ inline void gld16(const void* g, void* l) {
  __builtin_amdgcn_global_load_lds(
      (const __attribute__((address_space(1))) unsigned int*)g,
      (__attribute__((address_space(3))) unsigned int*)l, 16, 0, 0);
}
__device__ inline void gld4(const void* g, void* l) {
  __builtin_amdgcn_global_load_lds(
      (const __attribute__((address_space(1))) unsigned int*)g,
      (__attribute__((address_space(3))) unsigned int*)l, 4, 0, 0);
}

// ---------------------------------------------------------------- k_cvt
// Pre-convert codebook to hi/lo f16 planes (XOR-swizzled 16B chunks) + esq/2.
__global__ __launch_bounds__(256) void k_cvt(const float* __restrict__ e,
                                             float* __restrict__ ws) {
  int gid = blockIdx.x * 256 + threadIdx.x;
  if (gid == 0) {                            // ws is poisoned each run
    ws[WS_ACC] = 0.f;
    ((int*)ws)[WS_CNT] = 0;
  }
  int row = gid >> 3, c = gid & 7;
  const float* src = e + (size_t)row * DIM + c * 8;
  float4 a = *(const float4*)src;
  float4 b = *(const float4*)(src + 4);
  float x[8] = {a.x, a.y, a.z, a.w, b.x, b.y, b.z, b.w};
  float s = 0.f;
  half8 hv, lv;
  #pragma unroll
  for (int j = 0; j < 8; ++j) {
    s += x[j] * x[j];                        // esq in full fp32 from originals
    _Float16 h = (_Float16)x[j];
    hv[j] = h;
    lv[j] = (_Float16)(x[j] - (float)h);
  }
  s += __shfl_xor(s, 1); s += __shfl_xor(s, 2); s += __shfl_xor(s, 4);
  if (c == 0) ws[WS_ESQH + row] = 0.5f * s;
  int p = (c + row) & 7;                     // XOR/rotate swizzle within row
  ((half8*)(ws + WS_EHI))[row * 8 + p] = hv;
  ((half8*)(ws + WS_ELO))[row * 8 + p] = lv;
}

// ---------------------------------------------------------------- k_argmin
// Block: 64 voxels, 4 waves = 2 voxel-groups(32) x 2 code-halves.
// Distance surrogate per (voxel, code): t = esq/2 - dot (z_sq constant drops).
// dot via 3-term f16 split MFMA: hh + hl + lh (ll term ~2^-22 rel, dropped).
// Double-buffered LDS: stage tile ct+1 while computing ct (one barrier/tile).
// Fused epilogue: gather quantized rows, write indices, accumulate loss,
// last-block-done writes the scalar losses.
__global__ __launch_bounds__(256, 2) void k_argmin(const float* __restrict__ z,
                                                   const float* __restrict__ e,
                                                   float* __restrict__ ws,
                                                   float* __restrict__ out) {
  __shared__ __align__(16) _Float16 sBhi[2][128 * 64];   // 32 KB
  __shared__ __align__(16) _Float16 sBlo[2][128 * 64];   // 32 KB
  __shared__ float sEsq[2][128];                          // 1 KB
  __shared__ float sMval[128];
  __shared__ int   sMidx[128];
  __shared__ int   sWin[64];
  __shared__ float sWsum[4];

  const int tid  = threadIdx.x;
  const int lane = tid & 63;
  const int wave = tid >> 6;
  const int n16  = lane & 15;
  const int quad = lane >> 4;
  const int vgrp = wave >> 1;     // which 32-voxel group
  const int chalf = wave & 1;     // which 64-code half of the tile
  const int vb = blockIdx.x * 64;

  const char* ehi_b = (const char*)(ws + WS_EHI);
  const char* elo_b = (const char*)(ws + WS_ELO);
  const char* esq_b = (const char*)(ws + WS_ESQH);

  // A fragments: 32 voxels x 64 dims, hi/lo. A[m=lane&15][k=quad*8+j (+32*kc)]
  half8 ahi[2][2], alo[2][2];
  #pragma unroll
  for (int m = 0; m < 2; ++m)
    #pragma unroll
    for (int kc = 0; kc < 2; ++kc) {
      const float* src = z + (size_t)(vb + vgrp * 32 + m * 16 + n16) * DIM
                       + kc * 32 + quad * 8;
      float4 a = *(const float4*)src;
      float4 b = *(const float4*)(src + 4);
      float x[8] = {a.x, a.y, a.z, a.w, b.x, b.y, b.z, b.w};
      #pragma unroll
      for (int j = 0; j < 8; ++j) {
        _Float16 h = (_Float16)x[j];
        ahi[m][kc][j] = h;
        alo[m][kc][j] = (_Float16)(x[j] - (float)h);
      }
    }

  float bval[2][4]; int bidx[2][4];
  #pragma unroll
  for (int m = 0; m < 2; ++m)
    #pragma unroll
    for (int r = 0; r < 4; ++r) { bval[m][r] = FLT_MAX; bidx[m][r] = 0; }

  // swizzled chunk offsets (f16 units) for this lane's B-row reads
  const int s0 = ((quad + n16) & 7) * 8;          // kc=0 chunk
  const int s1 = ((quad + 4 + n16) & 7) * 8;      // kc=1 chunk

  // stage one 128-code tile (hi+lo planes + esq) into buffer buf
  auto stage = [&](int buf, int ct) {
    const size_t cbb = (size_t)ct * 128 * 128;    // bytes per plane-tile
    #pragma unroll
    for (int r = 0; r < 4; ++r) {
      int off = (r * 4 + wave) * 1024;            // wave-uniform LDS base
      gld16(ehi_b + cbb + off + lane * 16, (char*)sBhi[buf] + off);
      gld16(elo_b + cbb + off + lane * 16, (char*)sBlo[buf] + off);
    }
    if (wave == 0) {
      gld4(esq_b + (size_t)ct * 512 + lane * 4, (char*)sEsq[buf]);
      gld4(esq_b + (size_t)ct * 512 + 256 + lane * 4, (char*)sEsq[buf] + 256);
    }
  };

  stage(0, 0);
  __syncthreads();          // compiler drains vmcnt(0) before the barrier

  for (int ct = 0; ct < 64; ++ct) {
    const int cur = ct & 1;
    if (ct < 63) stage(cur ^ 1, ct + 1);          // prefetch next tile (async)

    const _Float16* bhiP = sBhi[cur];
    const _Float16* bloP = sBlo[cur];
    const float*    esqP = sEsq[cur];
    const int cb = ct * 128;

    #pragma unroll
    for (int t = 0; t < 4; ++t) {
      const int row = chalf * 64 + t * 16 + n16;
      half8 bh0 = *(const half8*)&bhiP[row * 64 + s0];
      half8 bh1 = *(const half8*)&bhiP[row * 64 + s1];
      half8 bl0 = *(const half8*)&bloP[row * 64 + s0];
      half8 bl1 = *(const half8*)&bloP[row * 64 + s1];
      float eh = esqP[row];
      int code = cb + row;
      #pragma unroll
      for (int m = 0; m < 2; ++m) {
        floatx4 acc = {0.f, 0.f, 0.f, 0.f};
        acc = __builtin_amdgcn_mfma_f32_16x16x32_f16(ahi[m][0], bh0, acc, 0, 0, 0);
        acc = __builtin_amdgcn_mfma_f32_16x16x32_f16(ahi[m][1], bh1, acc, 0, 0, 0);
        acc = __builtin_amdgcn_mfma_f32_16x16x32_f16(ahi[m][0], bl0, acc, 0, 0, 0);
        acc = __builtin_amdgcn_mfma_f32_16x16x32_f16(ahi[m][1], bl1, acc, 0, 0, 0);
        acc = __builtin_amdgcn_mfma_f32_16x16x32_f16(alo[m][0], bh0, acc, 0, 0, 0);
        acc = __builtin_amdgcn_mfma_f32_16x16x32_f16(alo[m][1], bh1, acc, 0, 0, 0);
        // C layout: col = lane&15 (code = this lane's row), row m_c = quad*4+r
        #pragma unroll
        for (int r = 0; r < 4; ++r) {
          float tv = eh - acc[r];
          if (tv < bval[m][r]) { bval[m][r] = tv; bidx[m][r] = code; }
        }
      }
    }
    __syncthreads();       // next-tile staging done + all reads of cur finished
  }

  // reduce across the 16 lanes (n16) holding each voxel's partials
  #pragma unroll
  for (int m = 0; m < 2; ++m)
    #pragma unroll
    for (int r = 0; r < 4; ++r) {
      float v = bval[m][r]; int i = bidx[m][r];
      #pragma unroll
      for (int off = 1; off < 16; off <<= 1) {
        float ov = __shfl_xor(v, off);
        int   oi = __shfl_xor(i, off);
        if (ov < v || (ov == v && oi < i)) { v = ov; i = oi; }
      }
      if (n16 == 0) {
        int vox = vgrp * 32 + m * 16 + quad * 4 + r;
        sMval[chalf * 64 + vox] = v;
        sMidx[chalf * 64 + vox] = i;
      }
    }
  __syncthreads();

  // merge the two code-halves, publish winner index
  if (tid < 64) {
    float v0 = sMval[tid], v1 = sMval[64 + tid];
    int   i0 = sMidx[tid], i1 = sMidx[64 + tid];
    bool p1 = (v1 < v0) || (v1 == v0 && i1 < i0);
    int w = p1 ? i1 : i0;
    sWin[tid] = w;
    out[IDX_OFF + vb + tid] = (float)w;
  }
  __syncthreads();

  // fused k_out: gather quantized rows (exact fp32), accumulate (z-q)^2
  {
    const int vox = tid >> 2;
    const int dc = (tid & 3) * 16;
    const int gi = sWin[vox];
    const float* er = e + (size_t)gi * DIM + dc;
    const float* zr = z + (size_t)(vb + vox) * DIM + dc;
    float* qr = out + Q_OFF + (size_t)(vb + vox) * DIM + dc;
    float local = 0.f;
    #pragma unroll
    for (int j = 0; j < 4; ++j) {
      float4 e4 = *(const float4*)(er + j * 4);
      float4 z4 = *(const float4*)(zr + j * 4);
      *(float4*)(qr + j * 4) = e4;
      float dx = z4.x - e4.x, dy = z4.y - e4.y, dz = z4.z - e4.z, dw = z4.w - e4.w;
      local += dx * dx + dy * dy + dz * dz + dw * dw;
    }
    #pragma unroll
    for (int off = 32; off; off >>= 1) local += __shfl_xor(local, off);
    if ((tid & 63) == 0) sWsum[wave] = local;
    __syncthreads();
    if (tid == 0) {
      float bs = sWsum[0] + sWsum[1] + sWsum[2] + sWsum[3];
      atomicAdd(ws + WS_ACC, bs);            // device-scope
      __threadfence();
      int done = atomicAdd((int*)ws + WS_CNT, 1);
      if (done == (int)gridDim.x - 1) {      // last block: finalize scalars
        float s = atomicAdd(ws + WS_ACC, 0.f);   // atomic read (coherent)
        float mv = s * (1.0f / (float)(N_VOX * DIM));
        out[VQ_OFF] = mv;   // vq_loss
        out[CM_OFF] = mv;   // commitment_loss (identical forward value)
      }
    }
  }
}

// ----------------------------------------------------------------
extern "C" void kernel_launch(void* const* d_in, const int* in_sizes, int n_in,
                              void* d_out, int out_size, void* d_ws, size_t ws_size,
                              hipStream_t stream) {
  const float* z = (const float*)d_in[0];
  const float* e = (const float*)d_in[1];
  float* out = (float*)d_out;
  float* ws = (float*)d_ws;

  k_cvt<<<(N_CODES * 8) / 256, 256, 0, stream>>>(e, ws);
  k_argmin<<<N_VOX / 64, 256, 0, stream>>>(z, e, ws, out);
}